// Round 8
// baseline (4224.880 us; speedup 1.0000x reference)
//
#include <hip/hip_runtime.h>

typedef float F2 __attribute__((ext_vector_type(2)));

#define NB 4
#define NC 17
#define T0 75000
#define NH 32
#define NK 8

// ---------------- diff precompute: D[b][c][t] = X[t+1]-X[t], D[T0-1]=0 ----------------
__global__ void diffK(const float* __restrict__ X, float* __restrict__ D) {
    int t = blockIdx.x * 256 + threadIdx.x;
    int row = blockIdx.y;
    if (t < T0) {
        size_t o = (size_t)row * T0 + t;
        D[o] = (t < T0 - 1) ? (X[o + 1] - X[o]) : 0.f;
    }
}

// pack k into low 3 mantissa bits; max/min trees carry the arg-index
__device__ __forceinline__ float packK(float z, int k) {
    unsigned u = (__float_as_uint(z) & 0xFFFFFFF8u) | (unsigned)k;
    return __uint_as_float(u);
}

// ---- packed-f32 helpers (gfx950 VOP3P: only fma/mul/add exist packed) --------------
__device__ __forceinline__ void pkfma_lo(F2& z, F2 g, unsigned long long w) {
    asm("v_pk_fma_f32 %0, %1, %2, %0 op_sel:[0,0,0] op_sel_hi:[1,0,1]"
        : "+v"(z) : "v"(g), "s"(w));
}
__device__ __forceinline__ void pkfma_hi(F2& z, F2 g, unsigned long long w) {
    asm("v_pk_fma_f32 %0, %1, %2, %0 op_sel:[0,1,0] op_sel_hi:[1,1,1]"
        : "+v"(z) : "v"(g), "s"(w));
}
__device__ __forceinline__ void pkmul_lo(F2& z, F2 g, unsigned long long w) {
    asm("v_pk_mul_f32 %0, %1, %2 op_sel:[0,0] op_sel_hi:[1,0]"
        : "=v"(z) : "v"(g), "s"(w));
}
__device__ __forceinline__ void pkmul_hi(F2& z, F2 g, unsigned long long w) {
    asm("v_pk_mul_f32 %0, %1, %2 op_sel:[0,1] op_sel_hi:[1,1]"
        : "=v"(z) : "v"(g), "s"(w));
}

// ---- epilogue (register form, kernA): scatter into VGPR accM + packed cnt ----------
template <int C>
__device__ __forceinline__ void epi8(const F2* Z, float* accM, unsigned long long& cnt) {
    float p[8];
#pragma unroll
    for (int k = 0; k < 8; ++k) p[k] = packK(C ? Z[k].y : Z[k].x, k);
    // nest as (a,b)->c chains so ISel can fuse to v_max3/v_min3
    float ma = fmaxf(fmaxf(p[0], p[1]), p[2]);
    float mb = fmaxf(fmaxf(p[3], p[4]), p[5]);
    float mc = fmaxf(fmaxf(p[6], p[7]), ma);
    float best = fmaxf(mb, mc);
    float na = fminf(fminf(p[0], p[1]), p[2]);
    float nb = fminf(fminf(p[3], p[4]), p[5]);
    float nc = fminf(fminf(p[6], p[7]), na);
    float worst = fminf(nb, nc);
    int biK = __float_as_uint(best) & 7;
    int wiK = __float_as_uint(worst) & 7;
#pragma unroll
    for (int k = 0; k < 8; ++k) accM[k] += (k == biK) ? best : 0.f;
    cnt += 1ull << (wiK << 3);
}

// ---- epilogue (pair-packed, kernB2): both positions into F2 acc2 -------------------
// Per k: 2 cmp + 2 cndmask + 1 v_pk_add (5 ops) vs 6 for two scalar scatters.
// Invalid component -> bNk=8 never matches k in [0,8): contributes 0.
__device__ __forceinline__ void epiPair(const F2* Z, F2* acc2, unsigned long long& cnt,
                                        bool mx, bool my) {
    F2 pp[8];
#pragma unroll
    for (int k = 0; k < 8; ++k) { pp[k].x = packK(Z[k].x, k); pp[k].y = packK(Z[k].y, k); }

    float xa = fmaxf(fmaxf(pp[0].x, pp[1].x), pp[2].x);
    float xb = fmaxf(fmaxf(pp[3].x, pp[4].x), pp[5].x);
    float xc = fmaxf(fmaxf(pp[6].x, pp[7].x), xa);
    float bx = fmaxf(xb, xc);
    float xna = fminf(fminf(pp[0].x, pp[1].x), pp[2].x);
    float xnb = fminf(fminf(pp[3].x, pp[4].x), pp[5].x);
    float xnc = fminf(fminf(pp[6].x, pp[7].x), xna);
    float wxv = fminf(xnb, xnc);

    float ya = fmaxf(fmaxf(pp[0].y, pp[1].y), pp[2].y);
    float yb = fmaxf(fmaxf(pp[3].y, pp[4].y), pp[5].y);
    float yc = fmaxf(fmaxf(pp[6].y, pp[7].y), ya);
    float by = fmaxf(yb, yc);
    float yna = fminf(fminf(pp[0].y, pp[1].y), pp[2].y);
    float ynb = fminf(fminf(pp[3].y, pp[4].y), pp[5].y);
    float ync = fminf(fminf(pp[6].y, pp[7].y), yna);
    float wyv = fminf(ynb, ync);

    int bxk = mx ? (int)(__float_as_uint(bx) & 7) : 8;
    int byk = my ? (int)(__float_as_uint(by) & 7) : 8;
#pragma unroll
    for (int k = 0; k < 8; ++k) {
        F2 sel;
        sel.x = (k == bxk) ? bx : 0.f;
        sel.y = (k == byk) ? by : 0.f;
        acc2[k] += sel;
    }
    int wxk = (int)(__float_as_uint(wxv) & 7);
    int wyk = (int)(__float_as_uint(wyv) & 7);
    unsigned long long incx = mx ? (1ull << (wxk << 3)) : 0ull;
    unsigned long long incy = my ? (1ull << (wyk << 3)) : 0ull;
    cnt += incx + incy;
}

// ---- conv for one position pair: j=0 as pk_mul (no Z init), j=1..8 pk_fma ----------
__device__ __forceinline__ void conv9(F2* Z, const F2* g9, const unsigned long long* wq) {
#pragma unroll
    for (int k = 0; k < 8; ++k) {
        const int wi = k * 9;
        if (wi & 1) pkmul_hi(Z[k], g9[0], wq[wi >> 1]);
        else        pkmul_lo(Z[k], g9[0], wq[wi >> 1]);
    }
#pragma unroll
    for (int j = 1; j < 9; ++j) {
#pragma unroll
        for (int k = 0; k < 8; ++k) {
            const int wi = k * 9 + j;
            if (wi & 1) pkfma_hi(Z[k], g9[j], wq[wi >> 1]);
            else        pkfma_lo(Z[k], g9[j], wq[wi >> 1]);
        }
    }
}

// ---------------- kernel A: di 0..5 (d = 1..32), LDS-tiled, 8 pos/thread ------------
// (exact round-4 form: best measured ~320 us — untouched)
constexpr int TS = 2048;
constexpr int A_TILES = 37;                     // 37*2048 = 75776 >= 75000
constexpr int A_BLOCKS_PER_G = 128 * A_TILES;   // 4736
constexpr int A_GROUPS = 12;
constexpr int A_TOTAL_BLOCKS = A_GROUPS * A_BLOCKS_PER_G;  // 56832

template <bool USE_D>
__global__ __launch_bounds__(256) void kernA(const float* __restrict__ X,
                                             const float* __restrict__ Dws,
                                             const float* __restrict__ Wt,
                                             const int* __restrict__ idx,
                                             float* __restrict__ out) {
    __shared__ float Sbuf[16 * 257];             // staging (<=2304) / reduction (4112)
    __shared__ float red[4][16];

    const int tid = threadIdx.x;
    const int bid = blockIdx.x;
    const int ga = bid / A_BLOCKS_PER_G;
    const int rem = bid - ga * A_BLOCKS_PER_G;
    const int b = rem & 3;                       // XCD locality: b fastest
    const int z = rem >> 2;
    const int h = z & 31;
    const int tile = z >> 5;
    const int di = ga >> 1, diff = ga & 1;
    const int d = 1 << di;
    const int T = T0 - diff;
    const int t0 = tile * TS;
    const int span = TS + 8 * d;                 // <= 2304
    const int g0 = t0 - 4 * d;                   // even

    const int* ip = idx + (ga * NH + h) * 8;
    int offs[8];
#pragma unroll
    for (int i = 0; i < 8; ++i)
        offs[i] = __builtin_amdgcn_readfirstlane((b * NC + ip[i]) * T0);

    if (USE_D) {
        const float* base = diff ? Dws : X;
        for (int e = tid * 2; e < span; e += 512) {
            int u = g0 + e;
            F2 s = {0.f, 0.f};
            if (u >= 0 && u + 1 < T0) {
#pragma unroll
                for (int i = 0; i < 8; ++i) s += *(const F2*)(base + offs[i] + u);
            } else {
#pragma unroll
                for (int c = 0; c < 2; ++c) {
                    int uc = u + c;
                    float sc = 0.f;
                    if (uc >= 0 && uc < T0) {
#pragma unroll
                        for (int i = 0; i < 8; ++i) sc += base[offs[i] + uc];
                    }
                    s[c] = sc;
                }
            }
            if (e + 1 < span) *(F2*)(Sbuf + e) = s;
            else Sbuf[e] = s.x;
        }
    } else {
        for (int ls = tid; ls < span; ls += 256) {
            int u = g0 + ls;
            float s = 0.f;
            if (diff) {
                if (u >= 0 && u < T0 - 1) {
#pragma unroll
                    for (int i = 0; i < 8; ++i) s += X[offs[i] + u + 1] - X[offs[i] + u];
                }
            } else {
                if (u >= 0 && u < T0) {
#pragma unroll
                    for (int i = 0; i < 8; ++i) s += X[offs[i] + u];
                }
            }
            Sbuf[ls] = s;
        }
    }
    __syncthreads();

    // weights: uniform 64-bit loads -> s_load into even-aligned SGPR pairs
    const int wbase = __builtin_amdgcn_readfirstlane((ga * (NK * NH) + h * NK) * 9);
    const unsigned long long* wq64 = (const unsigned long long*)(Wt + wbase);
    unsigned long long wq[36];
#pragma unroll
    for (int i = 0; i < 36; ++i) wq[i] = wq64[i];

    float accM[8];
#pragma unroll
    for (int k = 0; k < 8; ++k) accM[k] = 0.f;
    unsigned long long cnt = 0;                  // 8 x 8-bit min-count fields (<=8)

#pragma unroll
    for (int it = 0; it < 4; ++it) {
        int p = tid + it * 256;                  // pair: positions (t0+p, t0+p+1024)
        int t = t0 + p;
        F2 g9[9];
#pragma unroll
        for (int j = 0; j < 9; ++j) {
            g9[j].x = Sbuf[p + j * d];           // stride-1 across lanes: conflict-free
            g9[j].y = Sbuf[p + 1024 + j * d];
        }
        F2 Z[8];
        conv9(Z, g9, wq);
        if (t < T)        epi8<0>(Z, accM, cnt);
        if (t + 1024 < T) epi8<1>(Z, accM, cnt);
    }

    float accC[8];
#pragma unroll
    for (int k = 0; k < 8; ++k) accC[k] = (float)((unsigned)(cnt >> (k * 8)) & 255u);

    // LDS transpose reduction: rows 0..7 accM, 8..15 accC, stride 257 (conflict-free)
    __syncthreads();                             // main-loop Sbuf reads complete
#pragma unroll
    for (int k = 0; k < 8; ++k) {
        Sbuf[k * 257 + tid] = accM[k];
        Sbuf[(k + 8) * 257 + tid] = accC[k];
    }
    __syncthreads();
    {
        int k = tid & 15, seg = tid >> 4;        // reads: 2 lanes/bank (free)
        const float* rp = Sbuf + k * 257 + seg * 16;
        float s = 0.f;
#pragma unroll
        for (int i = 0; i < 16; ++i) s += rp[i];
        s += __shfl_xor(s, 16, 64);
        s += __shfl_xor(s, 32, 64);
        int wv = tid >> 6;
        if ((tid & 63) < 16) red[wv][k] = s;     // lane's k, wave-level sum
    }
    __syncthreads();
    if (tid < 16) {
        float v = red[0][tid] + red[1][tid] + red[2][tid] + red[3][tid];
        int which = tid >> 3;
        int k = tid & 7;
        int o = ga * 2 + which;
        atomicAdd(&out[(size_t)b * 14336 + (o * NH + h) * NK + k], v);
    }
}

// ---------------- kernel B2: di 6..13, phase-PAIR F2 register ring ----------------
struct BG2 { int base, segs2, di, diff; };       // base in blocks (blocks = 128*segs2/256)
constexpr BG2 BGS2[16] = {
    {0,     640,  6, 0}, {320,   640,  6, 1},
    {640,   640,  7, 0}, {960,   640,  7, 1},
    {1280,  640,  8, 0}, {1600,  640,  8, 1},
    {1920,  768,  9, 0}, {2304,  768,  9, 1},
    {2688, 1024, 10, 0}, {3200, 1024, 10, 1},
    {3712, 1024, 11, 0}, {4224, 1024, 11, 1},
    {4736, 2048, 12, 0}, {5760, 2048, 12, 1},
    {6784, 4096, 13, 0}, {8832, 4096, 13, 1},
};
constexpr int B2_BLOCKS = 10880;

// F2 gather via 8 UNIFORM scalar base pointers (SGPR pairs) + 32-bit unsigned index:
// enables global_load_dwordx2 saddr form — one shared voffset, no 64-bit vaddr math.
template <bool USE_D>
__device__ __forceinline__ F2 gather2(const float* const* __restrict__ bp,
                                      int u, int diffF) {
    F2 s = {0.f, 0.f};
    if (u >= 0 && u + 1 < T0) {                  // fast path: aligned dwordx2
        if (!USE_D && diffF) {
            float m0 = 0.f, m1 = 0.f, m2 = 0.f;
#pragma unroll
            for (int i = 0; i < 8; ++i) {
                const float* q = bp[i] + (unsigned)u;
                m0 += q[0];
                m1 += q[1];
                m2 += (u + 2 < T0) ? q[2] : q[1];
            }
            s.x = m1 - m0;
            s.y = (u + 2 < T0) ? (m2 - m1) : 0.f;
        } else {
#pragma unroll
            for (int i = 0; i < 8; ++i) s += *(const F2*)(bp[i] + (unsigned)u);
        }
    } else if (u + 1 >= 0 && u < T0) {           // edge: per-component
#pragma unroll
        for (int c = 0; c < 2; ++c) {
            int uc = u + c;
            float sc = 0.f;
            if (uc >= 0 && uc < T0) {
                if (!USE_D && diffF) {
                    if (uc < T0 - 1) {
#pragma unroll
                        for (int i = 0; i < 8; ++i)
                            sc += bp[i][(unsigned)uc + 1] - bp[i][(unsigned)uc];
                    }
                } else {
#pragma unroll
                    for (int i = 0; i < 8; ++i) sc += bp[i][(unsigned)uc];
                }
            }
            s[c] = sc;
        }
    }
    return s;
}

template <bool USE_D>
__global__ __launch_bounds__(256, 4) void kernB2(const float* __restrict__ X,
                                                 const float* __restrict__ Dws,
                                                 const float* __restrict__ Wt,
                                                 const int* __restrict__ idx,
                                                 float* __restrict__ out) {
    const int tid = threadIdx.x;
    const int bid = blockIdx.x;

    int di = 6, diff = 0, gig = 0, combo = 0, sg = 0;
#pragma unroll
    for (int g = 0; g < 16; ++g) {
        const int s2 = BGS2[g].segs2;
        if (bid >= BGS2[g].base && bid < BGS2[g].base + 128 * s2 / 256) {
            gig = (bid - BGS2[g].base) * 256 + tid;
            combo = gig / s2;                    // compile-time magic div
            sg = gig - combo * s2;
            di = BGS2[g].di; diff = BGS2[g].diff;
        }
    }
    combo = __builtin_amdgcn_readfirstlane(combo);   // wave-uniform (segs2 % 64 == 0)
    di    = __builtin_amdgcn_readfirstlane(di);
    diff  = __builtin_amdgcn_readfirstlane(diff);

    const int d = 1 << di;
    const int T = T0 - diff;
    const int Q = (T + d - 1) >> di;
    const int ga = di * 2 + diff;
    const int b = combo & 3;                     // XCD locality: b fastest
    const int h = combo >> 2;

    const int p = sg & ((d >> 1) - 1);
    const int q0 = (sg >> (di - 1)) * 60;        // per-lane ok
    const int r = 2 * p;

    const int* ip = idx + (ga * NH + h) * 8;
    int offs[8];
#pragma unroll
    for (int i = 0; i < 8; ++i)
        offs[i] = __builtin_amdgcn_readfirstlane((b * NC + ip[i]) * T0);

    // weights: uniform 64-bit loads -> s_load into even-aligned SGPR pairs
    const int wbase = __builtin_amdgcn_readfirstlane((ga * (NK * NH) + h * NK) * 9);
    const unsigned long long* wq64 = (const unsigned long long*)(Wt + wbase);
    unsigned long long wq[36];
#pragma unroll
    for (int i = 0; i < 36; ++i) wq[i] = wq64[i];

    const float* base = (USE_D && diff) ? Dws : X;
    const float* bp[8];                          // uniform scalar bases -> SGPR pairs
#pragma unroll
    for (int i = 0; i < 8; ++i) bp[i] = base + offs[i];

    F2 acc2[8];
#pragma unroll
    for (int k = 0; k < 8; ++k) acc2[k] = (F2){0.f, 0.f};
    unsigned long long cnt = 0;                  // 8 x 8-bit fields (<=120)

    const int t0 = r + q0 * d;
    F2 buf[12];                                  // slot m: t = t0 + (m-4)*d
    {
        int u = t0 - 4 * d;
#pragma unroll
        for (int m = 0; m < 12; ++m) { buf[m] = gather2<USE_D>(bp, u, diff); u += d; }
    }

    for (int outer = 0; outer < 5; ++outer) {
        if (q0 + outer * 12 >= Q) break;
        const int tb = t0 + outer * 12 * d;
        if (tb + 11 * d + 1 < T) {               // interior: all 24 positions valid
#pragma unroll
            for (int ii = 0; ii < 12; ++ii) {
                const int t = tb + ii * d;
                F2 g9[9];
#pragma unroll
                for (int j = 0; j < 9; ++j) g9[j] = buf[(ii + j) % 12];
                F2 Z[8];
                conv9(Z, g9, wq);
                epiPair(Z, acc2, cnt, true, true);
                buf[ii] = gather2<USE_D>(bp, t + 8 * d, diff);
            }
        } else {                                  // tail: guarded
#pragma unroll
            for (int ii = 0; ii < 12; ++ii) {
                const int t = tb + ii * d;
                F2 g9[9];
#pragma unroll
                for (int j = 0; j < 9; ++j) g9[j] = buf[(ii + j) % 12];
                F2 Z[8];
                conv9(Z, g9, wq);
                epiPair(Z, acc2, cnt, t < T, t + 1 < T);
                buf[ii] = gather2<USE_D>(bp, t + 8 * d, diff);
            }
        }
    }

    float accM[8];
#pragma unroll
    for (int k = 0; k < 8; ++k) accM[k] = acc2[k].x + acc2[k].y;
    float accC[8];
#pragma unroll
    for (int k = 0; k < 8; ++k) accC[k] = (float)((unsigned)(cnt >> (k * 8)) & 255u);

    // per-wave butterfly (combo wave-uniform; block may straddle combos)
#pragma unroll
    for (int k = 0; k < 8; ++k) {
#pragma unroll
        for (int sh = 1; sh < 64; sh <<= 1) {
            accM[k] += __shfl_xor(accM[k], sh, 64);
            accC[k] += __shfl_xor(accC[k], sh, 64);
        }
    }
    if ((tid & 63) == 0) {
        size_t bb = (size_t)b * 14336;
        int o = ga * 2;
#pragma unroll
        for (int k = 0; k < 8; ++k) {
            atomicAdd(&out[bb + (o * NH + h) * NK + k],       accM[k]);
            atomicAdd(&out[bb + ((o + 1) * NH + h) * NK + k], accC[k]);
        }
    }
}

__global__ void zeroK(float* __restrict__ out, int n) {
    int i = blockIdx.x * 256 + threadIdx.x;
    if (i < n) out[i] = 0.f;
}

extern "C" void kernel_launch(void* const* d_in, const int* in_sizes, int n_in,
                              void* d_out, int out_size, void* d_ws, size_t ws_size,
                              hipStream_t stream) {
    const float* X  = (const float*)d_in[0];
    const float* Wt = (const float*)d_in[1];
    const int*  idx = (const int*)d_in[2];
    float* out = (float*)d_out;
    float* Dws = (float*)d_ws;

    const size_t D_BYTES = (size_t)NB * NC * T0 * sizeof(float);   // 20.4 MB
    const bool useD = ws_size >= D_BYTES;

    zeroK<<<(out_size + 255) / 256, 256, 0, stream>>>(out, out_size);
    if (useD) {
        dim3 dg((T0 + 255) / 256, NB * NC);
        diffK<<<dg, 256, 0, stream>>>(X, Dws);
        kernA<true><<<A_TOTAL_BLOCKS, 256, 0, stream>>>(X, Dws, Wt, idx, out);
        kernB2<true><<<B2_BLOCKS, 256, 0, stream>>>(X, Dws, Wt, idx, out);
    } else {
        kernA<false><<<A_TOTAL_BLOCKS, 256, 0, stream>>>(X, Dws, Wt, idx, out);
        kernB2<false><<<B2_BLOCKS, 256, 0, stream>>>(X, Dws, Wt, idx, out);
    }
}

// Round 9
// 3467.817 us; speedup vs baseline: 1.2183x; 1.2183x over previous
//
#include <hip/hip_runtime.h>

typedef float F2 __attribute__((ext_vector_type(2)));

#define NB 4
#define NC 17
#define T0 75000
#define NH 32
#define NK 8

// ---------------- diff precompute: D[b][c][t] = X[t+1]-X[t], D[T0-1]=0 ----------------
__global__ void diffK(const float* __restrict__ X, float* __restrict__ D) {
    int t = blockIdx.x * 256 + threadIdx.x;
    int row = blockIdx.y;
    if (t < T0) {
        size_t o = (size_t)row * T0 + t;
        D[o] = (t < T0 - 1) ? (X[o + 1] - X[o]) : 0.f;
    }
}

// pack k into low 3 mantissa bits; max/min trees carry the arg-index
__device__ __forceinline__ float packK(float z, int k) {
    unsigned u = (__float_as_uint(z) & 0xFFFFFFF8u) | (unsigned)k;
    return __uint_as_float(u);
}

// ---- packed-f32 helpers (gfx950 VOP3P: only fma/mul/add exist packed) --------------
__device__ __forceinline__ void pkfma_lo(F2& z, F2 g, unsigned long long w) {
    asm("v_pk_fma_f32 %0, %1, %2, %0 op_sel:[0,0,0] op_sel_hi:[1,0,1]"
        : "+v"(z) : "v"(g), "s"(w));
}
__device__ __forceinline__ void pkfma_hi(F2& z, F2 g, unsigned long long w) {
    asm("v_pk_fma_f32 %0, %1, %2, %0 op_sel:[0,1,0] op_sel_hi:[1,1,1]"
        : "+v"(z) : "v"(g), "s"(w));
}
__device__ __forceinline__ void pkmul_lo(F2& z, F2 g, unsigned long long w) {
    asm("v_pk_mul_f32 %0, %1, %2 op_sel:[0,0] op_sel_hi:[1,0]"
        : "=v"(z) : "v"(g), "s"(w));
}
__device__ __forceinline__ void pkmul_hi(F2& z, F2 g, unsigned long long w) {
    asm("v_pk_mul_f32 %0, %1, %2 op_sel:[0,1] op_sel_hi:[1,1]"
        : "=v"(z) : "v"(g), "s"(w));
}

// ---- shared epilogue: one position (component C of the F2 results) -----------------
template <int C>
__device__ __forceinline__ void epi8(const F2* Z, float* accM, unsigned long long& cnt) {
    float p[8];
#pragma unroll
    for (int k = 0; k < 8; ++k) p[k] = packK(C ? Z[k].y : Z[k].x, k);
    // nest as (a,b)->c chains so ISel can fuse to v_max3/v_min3
    float ma = fmaxf(fmaxf(p[0], p[1]), p[2]);
    float mb = fmaxf(fmaxf(p[3], p[4]), p[5]);
    float mc = fmaxf(fmaxf(p[6], p[7]), ma);
    float best = fmaxf(mb, mc);
    float na = fminf(fminf(p[0], p[1]), p[2]);
    float nb = fminf(fminf(p[3], p[4]), p[5]);
    float nc = fminf(fminf(p[6], p[7]), na);
    float worst = fminf(nb, nc);
    int biK = __float_as_uint(best) & 7;
    int wiK = __float_as_uint(worst) & 7;
#pragma unroll
    for (int k = 0; k < 8; ++k) accM[k] += (k == biK) ? best : 0.f;
    cnt += 1ull << (wiK << 3);
}

// ---- conv for one position pair: j=0 as pk_mul (no Z init), j=1..8 pk_fma ----------
__device__ __forceinline__ void conv9(F2* Z, const F2* g9, const unsigned long long* wq) {
#pragma unroll
    for (int k = 0; k < 8; ++k) {
        const int wi = k * 9;
        if (wi & 1) pkmul_hi(Z[k], g9[0], wq[wi >> 1]);
        else        pkmul_lo(Z[k], g9[0], wq[wi >> 1]);
    }
#pragma unroll
    for (int j = 1; j < 9; ++j) {
#pragma unroll
        for (int k = 0; k < 8; ++k) {
            const int wi = k * 9 + j;
            if (wi & 1) pkfma_hi(Z[k], g9[j], wq[wi >> 1]);
            else        pkfma_lo(Z[k], g9[j], wq[wi >> 1]);
        }
    }
}

// ---------------- kernel A: di 0..5 (d = 1..32), LDS-tiled, 8 pos/thread ------------
// (exact round-4 form: best measured ~320 us — untouched)
constexpr int TS = 2048;
constexpr int A_TILES = 37;                     // 37*2048 = 75776 >= 75000
constexpr int A_BLOCKS_PER_G = 128 * A_TILES;   // 4736
constexpr int A_GROUPS = 12;
constexpr int A_TOTAL_BLOCKS = A_GROUPS * A_BLOCKS_PER_G;  // 56832

template <bool USE_D>
__global__ __launch_bounds__(256) void kernA(const float* __restrict__ X,
                                             const float* __restrict__ Dws,
                                             const float* __restrict__ Wt,
                                             const int* __restrict__ idx,
                                             float* __restrict__ out) {
    __shared__ float Sbuf[16 * 257];             // staging (<=2304) / reduction (4112)
    __shared__ float red[4][16];

    const int tid = threadIdx.x;
    const int bid = blockIdx.x;
    const int ga = bid / A_BLOCKS_PER_G;
    const int rem = bid - ga * A_BLOCKS_PER_G;
    const int b = rem & 3;                       // XCD locality: b fastest
    const int z = rem >> 2;
    const int h = z & 31;
    const int tile = z >> 5;
    const int di = ga >> 1, diff = ga & 1;
    const int d = 1 << di;
    const int T = T0 - diff;
    const int t0 = tile * TS;
    const int span = TS + 8 * d;                 // <= 2304
    const int g0 = t0 - 4 * d;                   // even

    const int* ip = idx + (ga * NH + h) * 8;
    int offs[8];
#pragma unroll
    for (int i = 0; i < 8; ++i)
        offs[i] = __builtin_amdgcn_readfirstlane((b * NC + ip[i]) * T0);

    if (USE_D) {
        const float* base = diff ? Dws : X;
        for (int e = tid * 2; e < span; e += 512) {
            int u = g0 + e;
            F2 s = {0.f, 0.f};
            if (u >= 0 && u + 1 < T0) {
#pragma unroll
                for (int i = 0; i < 8; ++i) s += *(const F2*)(base + offs[i] + u);
            } else {
#pragma unroll
                for (int c = 0; c < 2; ++c) {
                    int uc = u + c;
                    float sc = 0.f;
                    if (uc >= 0 && uc < T0) {
#pragma unroll
                        for (int i = 0; i < 8; ++i) sc += base[offs[i] + uc];
                    }
                    s[c] = sc;
                }
            }
            if (e + 1 < span) *(F2*)(Sbuf + e) = s;
            else Sbuf[e] = s.x;
        }
    } else {
        for (int ls = tid; ls < span; ls += 256) {
            int u = g0 + ls;
            float s = 0.f;
            if (diff) {
                if (u >= 0 && u < T0 - 1) {
#pragma unroll
                    for (int i = 0; i < 8; ++i) s += X[offs[i] + u + 1] - X[offs[i] + u];
                }
            } else {
                if (u >= 0 && u < T0) {
#pragma unroll
                    for (int i = 0; i < 8; ++i) s += X[offs[i] + u];
                }
            }
            Sbuf[ls] = s;
        }
    }
    __syncthreads();

    // weights: uniform 64-bit loads -> s_load into even-aligned SGPR pairs
    const int wbase = __builtin_amdgcn_readfirstlane((ga * (NK * NH) + h * NK) * 9);
    const unsigned long long* wq64 = (const unsigned long long*)(Wt + wbase);
    unsigned long long wq[36];
#pragma unroll
    for (int i = 0; i < 36; ++i) wq[i] = wq64[i];

    float accM[8];
#pragma unroll
    for (int k = 0; k < 8; ++k) accM[k] = 0.f;
    unsigned long long cnt = 0;                  // 8 x 8-bit min-count fields (<=8)

#pragma unroll
    for (int it = 0; it < 4; ++it) {
        int p = tid + it * 256;                  // pair: positions (t0+p, t0+p+1024)
        int t = t0 + p;
        F2 g9[9];
#pragma unroll
        for (int j = 0; j < 9; ++j) {
            g9[j].x = Sbuf[p + j * d];           // stride-1 across lanes: conflict-free
            g9[j].y = Sbuf[p + 1024 + j * d];
        }
        F2 Z[8];
        conv9(Z, g9, wq);
        if (t < T)        epi8<0>(Z, accM, cnt);
        if (t + 1024 < T) epi8<1>(Z, accM, cnt);
    }

    float accC[8];
#pragma unroll
    for (int k = 0; k < 8; ++k) accC[k] = (float)((unsigned)(cnt >> (k * 8)) & 255u);

    // LDS transpose reduction: rows 0..7 accM, 8..15 accC, stride 257 (conflict-free)
    __syncthreads();                             // main-loop Sbuf reads complete
#pragma unroll
    for (int k = 0; k < 8; ++k) {
        Sbuf[k * 257 + tid] = accM[k];
        Sbuf[(k + 8) * 257 + tid] = accC[k];
    }
    __syncthreads();
    {
        int k = tid & 15, seg = tid >> 4;        // reads: 2 lanes/bank (free)
        const float* rp = Sbuf + k * 257 + seg * 16;
        float s = 0.f;
#pragma unroll
        for (int i = 0; i < 16; ++i) s += rp[i];
        s += __shfl_xor(s, 16, 64);
        s += __shfl_xor(s, 32, 64);
        int wv = tid >> 6;
        if ((tid & 63) < 16) red[wv][k] = s;     // lane's k, wave-level sum
    }
    __syncthreads();
    if (tid < 16) {
        float v = red[0][tid] + red[1][tid] + red[2][tid] + red[3][tid];
        int which = tid >> 3;
        int k = tid & 7;
        int o = ga * 2 + which;
        atomicAdd(&out[(size_t)b * 14336 + (o * NH + h) * NK + k], v);
    }
}

// ---------------- kernel B2: di 6..13, phase-PAIR F2 register ring ----------------
struct BG2 { int base, segs2, di, diff; };       // base in blocks (blocks = 128*segs2/256)
constexpr BG2 BGS2[16] = {
    {0,     640,  6, 0}, {320,   640,  6, 1},
    {640,   640,  7, 0}, {960,   640,  7, 1},
    {1280,  640,  8, 0}, {1600,  640,  8, 1},
    {1920,  768,  9, 0}, {2304,  768,  9, 1},
    {2688, 1024, 10, 0}, {3200, 1024, 10, 1},
    {3712, 1024, 11, 0}, {4224, 1024, 11, 1},
    {4736, 2048, 12, 0}, {5760, 2048, 12, 1},
    {6784, 4096, 13, 0}, {8832, 4096, 13, 1},
};
constexpr int B2_BLOCKS = 10880;

// F2 gather {S[u], S[u+1]} with zero outside [0, T0). For USE_D diff rows,
// D[T0-1]=0 already encodes the logical zero-pad at T-1.
// NOTE (r8 lesson): offs passed as value array indexed only by constants after full
// inlining — do NOT convert to a pointer array (forces scratch, 8 GB spill traffic).
template <bool USE_D>
__device__ __forceinline__ F2 gather2(const float* __restrict__ base,
                                      const int* offs, int u, int diffF) {
    F2 s = {0.f, 0.f};
    if (u >= 0 && u + 1 < T0) {                  // fast path: aligned dwordx2
        if (!USE_D && diffF) {
            float m0 = 0.f, m1 = 0.f, m2 = 0.f;
#pragma unroll
            for (int i = 0; i < 8; ++i) {
                m0 += base[offs[i] + u];
                m1 += base[offs[i] + u + 1];
                m2 += (u + 2 < T0) ? base[offs[i] + u + 2] : base[offs[i] + u + 1];
            }
            s.x = m1 - m0;
            s.y = (u + 2 < T0) ? (m2 - m1) : 0.f;
        } else {
#pragma unroll
            for (int i = 0; i < 8; ++i) s += *(const F2*)(base + offs[i] + u);
        }
    } else if (u + 1 >= 0 && u < T0) {           // edge: per-component
#pragma unroll
        for (int c = 0; c < 2; ++c) {
            int uc = u + c;
            float sc = 0.f;
            if (uc >= 0 && uc < T0) {
                if (!USE_D && diffF) {
                    if (uc < T0 - 1) {
#pragma unroll
                        for (int i = 0; i < 8; ++i)
                            sc += base[offs[i] + uc + 1] - base[offs[i] + uc];
                    }
                } else {
#pragma unroll
                    for (int i = 0; i < 8; ++i) sc += base[offs[i] + uc];
                }
            }
            s[c] = sc;
        }
    }
    return s;
}

template <bool USE_D>
__global__ __launch_bounds__(256, 4) void kernB2(const float* __restrict__ X,
                                                 const float* __restrict__ Dws,
                                                 const float* __restrict__ Wt,
                                                 const int* __restrict__ idx,
                                                 float* __restrict__ out) {
    const int tid = threadIdx.x;
    const int bid = blockIdx.x;

    int di = 6, diff = 0, gig = 0, combo = 0, sg = 0;
#pragma unroll
    for (int g = 0; g < 16; ++g) {
        const int s2 = BGS2[g].segs2;
        if (bid >= BGS2[g].base && bid < BGS2[g].base + 128 * s2 / 256) {
            gig = (bid - BGS2[g].base) * 256 + tid;
            combo = gig / s2;                    // compile-time magic div
            sg = gig - combo * s2;
            di = BGS2[g].di; diff = BGS2[g].diff;
        }
    }
    combo = __builtin_amdgcn_readfirstlane(combo);   // wave-uniform (segs2 % 64 == 0)
    di    = __builtin_amdgcn_readfirstlane(di);
    diff  = __builtin_amdgcn_readfirstlane(diff);

    const int d = 1 << di;
    const int T = T0 - diff;
    const int Q = (T + d - 1) >> di;
    const int ga = di * 2 + diff;
    const int b = combo & 3;                     // XCD locality: b fastest
    const int h = combo >> 2;

    const int p = sg & ((d >> 1) - 1);
    const int q0 = (sg >> (di - 1)) * 60;        // per-lane ok
    const int r = 2 * p;

    const int* ip = idx + (ga * NH + h) * 8;
    int offs[8];
#pragma unroll
    for (int i = 0; i < 8; ++i)
        offs[i] = __builtin_amdgcn_readfirstlane((b * NC + ip[i]) * T0);

    // weights: uniform 64-bit loads -> s_load into even-aligned SGPR pairs
    const int wbase = __builtin_amdgcn_readfirstlane((ga * (NK * NH) + h * NK) * 9);
    const unsigned long long* wq64 = (const unsigned long long*)(Wt + wbase);
    unsigned long long wq[36];
#pragma unroll
    for (int i = 0; i < 36; ++i) wq[i] = wq64[i];

    const float* base = (USE_D && diff) ? Dws : X;

    float accM[8];
#pragma unroll
    for (int k = 0; k < 8; ++k) accM[k] = 0.f;
    unsigned long long cnt = 0;                  // 8 x 8-bit fields (<=120)

    const int t0 = r + q0 * d;
    F2 buf[12];                                  // slot m: t = t0 + (m-4)*d
    {
        int u = t0 - 4 * d;
#pragma unroll
        for (int m = 0; m < 12; ++m) { buf[m] = gather2<USE_D>(base, offs, u, diff); u += d; }
    }

    for (int outer = 0; outer < 5; ++outer) {
        if (q0 + outer * 12 >= Q) break;
        const int tb = t0 + outer * 12 * d;
        if (tb + 11 * d + 1 < T) {               // interior: all 24 positions valid
#pragma unroll
            for (int ii = 0; ii < 12; ++ii) {
                const int t = tb + ii * d;
                F2 g9[9];
#pragma unroll
                for (int j = 0; j < 9; ++j) g9[j] = buf[(ii + j) % 12];
                F2 Z[8];
                conv9(Z, g9, wq);
                epi8<0>(Z, accM, cnt);           // unguarded: no cmp/cndmask
                epi8<1>(Z, accM, cnt);
                buf[ii] = gather2<USE_D>(base, offs, t + 8 * d, diff);
            }
        } else {                                  // tail: guarded (rare)
#pragma unroll
            for (int ii = 0; ii < 12; ++ii) {
                const int t = tb + ii * d;
                F2 g9[9];
#pragma unroll
                for (int j = 0; j < 9; ++j) g9[j] = buf[(ii + j) % 12];
                F2 Z[8];
                conv9(Z, g9, wq);
                if (t < T)     epi8<0>(Z, accM, cnt);
                if (t + 1 < T) epi8<1>(Z, accM, cnt);
                buf[ii] = gather2<USE_D>(base, offs, t + 8 * d, diff);
            }
        }
    }

    float accC[8];
#pragma unroll
    for (int k = 0; k < 8; ++k) accC[k] = (float)((unsigned)(cnt >> (k * 8)) & 255u);

    // per-wave butterfly (combo wave-uniform; block may straddle combos)
#pragma unroll
    for (int k = 0; k < 8; ++k) {
#pragma unroll
        for (int sh = 1; sh < 64; sh <<= 1) {
            accM[k] += __shfl_xor(accM[k], sh, 64);
            accC[k] += __shfl_xor(accC[k], sh, 64);
        }
    }
    if ((tid & 63) == 0) {
        size_t bb = (size_t)b * 14336;
        int o = ga * 2;
#pragma unroll
        for (int k = 0; k < 8; ++k) {
            atomicAdd(&out[bb + (o * NH + h) * NK + k],       accM[k]);
            atomicAdd(&out[bb + ((o + 1) * NH + h) * NK + k], accC[k]);
        }
    }
}

__global__ void zeroK(float* __restrict__ out, int n) {
    int i = blockIdx.x * 256 + threadIdx.x;
    if (i < n) out[i] = 0.f;
}

extern "C" void kernel_launch(void* const* d_in, const int* in_sizes, int n_in,
                              void* d_out, int out_size, void* d_ws, size_t ws_size,
                              hipStream_t stream) {
    const float* X  = (const float*)d_in[0];
    const float* Wt = (const float*)d_in[1];
    const int*  idx = (const int*)d_in[2];
    float* out = (float*)d_out;
    float* Dws = (float*)d_ws;

    const size_t D_BYTES = (size_t)NB * NC * T0 * sizeof(float);   // 20.4 MB
    const bool useD = ws_size >= D_BYTES;

    zeroK<<<(out_size + 255) / 256, 256, 0, stream>>>(out, out_size);
    if (useD) {
        dim3 dg((T0 + 255) / 256, NB * NC);
        diffK<<<dg, 256, 0, stream>>>(X, Dws);
        kernA<true><<<A_TOTAL_BLOCKS, 256, 0, stream>>>(X, Dws, Wt, idx, out);
        kernB2<true><<<B2_BLOCKS, 256, 0, stream>>>(X, Dws, Wt, idx, out);
    } else {
        kernA<false><<<A_TOTAL_BLOCKS, 256, 0, stream>>>(X, Dws, Wt, idx, out);
        kernB2<false><<<B2_BLOCKS, 256, 0, stream>>>(X, Dws, Wt, idx, out);
    }
}

// Round 10
// 934.855 us; speedup vs baseline: 4.5193x; 3.7095x over previous
//
#include <hip/hip_runtime.h>

typedef float F2 __attribute__((ext_vector_type(2)));

#define NB 4
#define NC 17
#define T0 75000
#define NH 32
#define NK 8

// ---------------- diff precompute: D[b][c][t] = X[t+1]-X[t], D[T0-1]=0 ----------------
__global__ void diffK(const float* __restrict__ X, float* __restrict__ D) {
    int t = blockIdx.x * 256 + threadIdx.x;
    int row = blockIdx.y;
    if (t < T0) {
        size_t o = (size_t)row * T0 + t;
        D[o] = (t < T0 - 1) ? (X[o + 1] - X[o]) : 0.f;
    }
}

// pack k into low 3 mantissa bits; max/min trees carry the arg-index
__device__ __forceinline__ float packK(float z, int k) {
    unsigned u = (__float_as_uint(z) & 0xFFFFFFF8u) | (unsigned)k;
    return __uint_as_float(u);
}

// ---- packed-f32 helpers (gfx950 VOP3P: only fma/mul/add exist packed) --------------
__device__ __forceinline__ void pkfma_lo(F2& z, F2 g, unsigned long long w) {
    asm("v_pk_fma_f32 %0, %1, %2, %0 op_sel:[0,0,0] op_sel_hi:[1,0,1]"
        : "+v"(z) : "v"(g), "s"(w));
}
__device__ __forceinline__ void pkfma_hi(F2& z, F2 g, unsigned long long w) {
    asm("v_pk_fma_f32 %0, %1, %2, %0 op_sel:[0,1,0] op_sel_hi:[1,1,1]"
        : "+v"(z) : "v"(g), "s"(w));
}
__device__ __forceinline__ void pkmul_lo(F2& z, F2 g, unsigned long long w) {
    asm("v_pk_mul_f32 %0, %1, %2 op_sel:[0,0] op_sel_hi:[1,0]"
        : "=v"(z) : "v"(g), "s"(w));
}
__device__ __forceinline__ void pkmul_hi(F2& z, F2 g, unsigned long long w) {
    asm("v_pk_mul_f32 %0, %1, %2 op_sel:[0,1] op_sel_hi:[1,1]"
        : "=v"(z) : "v"(g), "s"(w));
}

// ---- shared epilogue: one position (component C of the F2 results) -----------------
template <int C>
__device__ __forceinline__ void epi8(const F2* Z, float* accM, unsigned long long& cnt) {
    float p[8];
#pragma unroll
    for (int k = 0; k < 8; ++k) p[k] = packK(C ? Z[k].y : Z[k].x, k);
    // nest as (a,b)->c chains so ISel can fuse to v_max3/v_min3
    float ma = fmaxf(fmaxf(p[0], p[1]), p[2]);
    float mb = fmaxf(fmaxf(p[3], p[4]), p[5]);
    float mc = fmaxf(fmaxf(p[6], p[7]), ma);
    float best = fmaxf(mb, mc);
    float na = fminf(fminf(p[0], p[1]), p[2]);
    float nb = fminf(fminf(p[3], p[4]), p[5]);
    float nc = fminf(fminf(p[6], p[7]), na);
    float worst = fminf(nb, nc);
    int biK = __float_as_uint(best) & 7;
    int wiK = __float_as_uint(worst) & 7;
#pragma unroll
    for (int k = 0; k < 8; ++k) accM[k] += (k == biK) ? best : 0.f;
    cnt += 1ull << (wiK << 3);
}

// ---- conv for one position pair: j=0 as pk_mul (no Z init), j=1..8 pk_fma ----------
__device__ __forceinline__ void conv9(F2* Z, const F2* g9, const unsigned long long* wq) {
#pragma unroll
    for (int k = 0; k < 8; ++k) {
        const int wi = k * 9;
        if (wi & 1) pkmul_hi(Z[k], g9[0], wq[wi >> 1]);
        else        pkmul_lo(Z[k], g9[0], wq[wi >> 1]);
    }
#pragma unroll
    for (int j = 1; j < 9; ++j) {
#pragma unroll
        for (int k = 0; k < 8; ++k) {
            const int wi = k * 9 + j;
            if (wi & 1) pkfma_hi(Z[k], g9[j], wq[wi >> 1]);
            else        pkfma_lo(Z[k], g9[j], wq[wi >> 1]);
        }
    }
}

// ---------------- kernel A: di 0..5 (d = 1..32), LDS-tiled, 8 pos/thread ------------
constexpr int TS = 2048;
constexpr int A_TILES = 37;                     // 37*2048 = 75776 >= 75000
constexpr int A_BLOCKS_PER_G = 128 * A_TILES;   // 4736
constexpr int A_GROUPS = 12;
constexpr int A_TOTAL_BLOCKS = A_GROUPS * A_BLOCKS_PER_G;  // 56832

template <bool USE_D>
__global__ __launch_bounds__(256) void kernA(const float* __restrict__ X,
                                             const float* __restrict__ Dws,
                                             const float* __restrict__ Wt,
                                             const int* __restrict__ idx,
                                             float* __restrict__ out) {
    __shared__ float Sbuf[16 * 257];             // staging (<=2304) / reduction (4112)
    __shared__ float red[4][16];

    const int tid = threadIdx.x;
    const int bid = blockIdx.x;
    const int ga = bid / A_BLOCKS_PER_G;
    const int rem = bid - ga * A_BLOCKS_PER_G;
    const int b = rem & 3;                       // XCD locality: b fastest
    const int z = rem >> 2;
    const int h = z & 31;
    const int tile = z >> 5;
    const int di = ga >> 1, diff = ga & 1;
    const int d = 1 << di;
    const int T = T0 - diff;
    const int t0 = tile * TS;
    const int span = TS + 8 * d;                 // <= 2304
    const int g0 = t0 - 4 * d;                   // even

    const int* ip = idx + (ga * NH + h) * 8;
    int offs[8];
#pragma unroll
    for (int i = 0; i < 8; ++i)
        offs[i] = __builtin_amdgcn_readfirstlane((b * NC + ip[i]) * T0);

    if (USE_D) {
        const float* base = diff ? Dws : X;
        for (int e = tid * 2; e < span; e += 512) {
            int u = g0 + e;
            F2 s = {0.f, 0.f};
            if (u >= 0 && u + 1 < T0) {
#pragma unroll
                for (int i = 0; i < 8; ++i) s += *(const F2*)(base + offs[i] + u);
            } else {
#pragma unroll
                for (int c = 0; c < 2; ++c) {
                    int uc = u + c;
                    float sc = 0.f;
                    if (uc >= 0 && uc < T0) {
#pragma unroll
                        for (int i = 0; i < 8; ++i) sc += base[offs[i] + uc];
                    }
                    s[c] = sc;
                }
            }
            if (e + 1 < span) *(F2*)(Sbuf + e) = s;
            else Sbuf[e] = s.x;
        }
    } else {
        for (int ls = tid; ls < span; ls += 256) {
            int u = g0 + ls;
            float s = 0.f;
            if (diff) {
                if (u >= 0 && u < T0 - 1) {
#pragma unroll
                    for (int i = 0; i < 8; ++i) s += X[offs[i] + u + 1] - X[offs[i] + u];
                }
            } else {
                if (u >= 0 && u < T0) {
#pragma unroll
                    for (int i = 0; i < 8; ++i) s += X[offs[i] + u];
                }
            }
            Sbuf[ls] = s;
        }
    }
    __syncthreads();

    // weights: uniform 64-bit loads -> s_load into even-aligned SGPR pairs
    const int wbase = __builtin_amdgcn_readfirstlane((ga * (NK * NH) + h * NK) * 9);
    const unsigned long long* wq64 = (const unsigned long long*)(Wt + wbase);
    unsigned long long wq[36];
#pragma unroll
    for (int i = 0; i < 36; ++i) wq[i] = wq64[i];

    float accM[8];
#pragma unroll
    for (int k = 0; k < 8; ++k) accM[k] = 0.f;
    unsigned long long cnt = 0;                  // 8 x 8-bit min-count fields (<=8)

#pragma unroll
    for (int it = 0; it < 4; ++it) {
        int p = tid + it * 256;                  // pair: positions (t0+p, t0+p+1024)
        int t = t0 + p;
        F2 g9[9];
#pragma unroll
        for (int j = 0; j < 9; ++j) {
            g9[j].x = Sbuf[p + j * d];           // stride-1 across lanes: conflict-free
            g9[j].y = Sbuf[p + 1024 + j * d];
        }
        F2 Z[8];
        conv9(Z, g9, wq);
        if (t < T)        epi8<0>(Z, accM, cnt);
        if (t + 1024 < T) epi8<1>(Z, accM, cnt);
    }

    float accC[8];
#pragma unroll
    for (int k = 0; k < 8; ++k) accC[k] = (float)((unsigned)(cnt >> (k * 8)) & 255u);

    // LDS transpose reduction: rows 0..7 accM, 8..15 accC, stride 257 (conflict-free)
    __syncthreads();                             // main-loop Sbuf reads complete
#pragma unroll
    for (int k = 0; k < 8; ++k) {
        Sbuf[k * 257 + tid] = accM[k];
        Sbuf[(k + 8) * 257 + tid] = accC[k];
    }
    __syncthreads();
    {
        int k = tid & 15, seg = tid >> 4;        // reads: 2 lanes/bank (free)
        const float* rp = Sbuf + k * 257 + seg * 16;
        float s = 0.f;
#pragma unroll
        for (int i = 0; i < 16; ++i) s += rp[i];
        s += __shfl_xor(s, 16, 64);
        s += __shfl_xor(s, 32, 64);
        int wv = tid >> 6;
        if ((tid & 63) < 16) red[wv][k] = s;     // lane's k, wave-level sum
    }
    __syncthreads();
    if (tid < 16) {
        float v = red[0][tid] + red[1][tid] + red[2][tid] + red[3][tid];
        int which = tid >> 3;
        int k = tid & 7;
        int o = ga * 2 + which;
        atomicAdd(&out[(size_t)b * 14336 + (o * NH + h) * NK + k], v);
    }
}

// ---------------- kernel B2: di 6..13, phase-PAIR F2 register ring ----------------
struct BG2 { int base, segs2, di, diff; };       // base in blocks (blocks = 128*segs2/256)
constexpr BG2 BGS2[16] = {
    {0,     640,  6, 0}, {320,   640,  6, 1},
    {640,   640,  7, 0}, {960,   640,  7, 1},
    {1280,  640,  8, 0}, {1600,  640,  8, 1},
    {1920,  768,  9, 0}, {2304,  768,  9, 1},
    {2688, 1024, 10, 0}, {3200, 1024, 10, 1},
    {3712, 1024, 11, 0}, {4224, 1024, 11, 1},
    {4736, 2048, 12, 0}, {5760, 2048, 12, 1},
    {6784, 4096, 13, 0}, {8832, 4096, 13, 1},
};
constexpr int B2_BLOCKS = 10880;

// F2 gather {S[u], S[u+1]} with zero outside [0, T0). For USE_D diff rows,
// D[T0-1]=0 already encodes the logical zero-pad at T-1.
// NOTE (r8/r9 lessons): keep EXACTLY this shape. Pointer-array bases -> scratch
// (8 GB spill, r8). Duplicating the unrolled inner loop -> partial unroll ->
// dynamic buf indexing -> scratch (5.7 GB spill, r9).
template <bool USE_D>
__device__ __forceinline__ F2 gather2(const float* __restrict__ base,
                                      const int* offs, int u, int diffF) {
    F2 s = {0.f, 0.f};
    if (u >= 0 && u + 1 < T0) {                  // fast path: aligned dwordx2
        if (!USE_D && diffF) {
            float m0 = 0.f, m1 = 0.f, m2 = 0.f;
#pragma unroll
            for (int i = 0; i < 8; ++i) {
                m0 += base[offs[i] + u];
                m1 += base[offs[i] + u + 1];
                m2 += (u + 2 < T0) ? base[offs[i] + u + 2] : base[offs[i] + u + 1];
            }
            s.x = m1 - m0;
            s.y = (u + 2 < T0) ? (m2 - m1) : 0.f;
        } else {
#pragma unroll
            for (int i = 0; i < 8; ++i) s += *(const F2*)(base + offs[i] + u);
        }
    } else if (u + 1 >= 0 && u < T0) {           // edge: per-component
#pragma unroll
        for (int c = 0; c < 2; ++c) {
            int uc = u + c;
            float sc = 0.f;
            if (uc >= 0 && uc < T0) {
                if (!USE_D && diffF) {
                    if (uc < T0 - 1) {
#pragma unroll
                        for (int i = 0; i < 8; ++i)
                            sc += base[offs[i] + uc + 1] - base[offs[i] + uc];
                    }
                } else {
#pragma unroll
                    for (int i = 0; i < 8; ++i) sc += base[offs[i] + uc];
                }
            }
            s[c] = sc;
        }
    }
    return s;
}

template <bool USE_D>
__global__ __launch_bounds__(256, 4) void kernB2(const float* __restrict__ X,
                                                 const float* __restrict__ Dws,
                                                 const float* __restrict__ Wt,
                                                 const int* __restrict__ idx,
                                                 float* __restrict__ out) {
    const int tid = threadIdx.x;
    const int bid = blockIdx.x;

    int di = 6, diff = 0, gig = 0, combo = 0, sg = 0;
#pragma unroll
    for (int g = 0; g < 16; ++g) {
        const int s2 = BGS2[g].segs2;
        if (bid >= BGS2[g].base && bid < BGS2[g].base + 128 * s2 / 256) {
            gig = (bid - BGS2[g].base) * 256 + tid;
            combo = gig / s2;                    // compile-time magic div
            sg = gig - combo * s2;
            di = BGS2[g].di; diff = BGS2[g].diff;
        }
    }
    combo = __builtin_amdgcn_readfirstlane(combo);   // wave-uniform (segs2 % 64 == 0)
    di    = __builtin_amdgcn_readfirstlane(di);
    diff  = __builtin_amdgcn_readfirstlane(diff);

    const int d = 1 << di;
    const int T = T0 - diff;
    const int Q = (T + d - 1) >> di;
    const int ga = di * 2 + diff;
    const int b = combo & 3;                     // XCD locality: b fastest
    const int h = combo >> 2;

    const int p = sg & ((d >> 1) - 1);
    const int q0 = (sg >> (di - 1)) * 60;        // per-lane ok
    const int r = 2 * p;

    const int* ip = idx + (ga * NH + h) * 8;
    int offs[8];
#pragma unroll
    for (int i = 0; i < 8; ++i)
        offs[i] = __builtin_amdgcn_readfirstlane((b * NC + ip[i]) * T0);

    // weights: uniform 64-bit loads -> s_load into even-aligned SGPR pairs
    const int wbase = __builtin_amdgcn_readfirstlane((ga * (NK * NH) + h * NK) * 9);
    const unsigned long long* wq64 = (const unsigned long long*)(Wt + wbase);
    unsigned long long wq[36];
#pragma unroll
    for (int i = 0; i < 36; ++i) wq[i] = wq64[i];

    const float* base = (USE_D && diff) ? Dws : X;

    float accM[8];
#pragma unroll
    for (int k = 0; k < 8; ++k) accM[k] = 0.f;
    unsigned long long cnt = 0;                  // 8 x 8-bit fields (<=120)

    const int t0 = r + q0 * d;
    F2 buf[12];                                  // slot m: t = t0 + (m-4)*d
    {
        int u = t0 - 4 * d;
#pragma unroll
        for (int m = 0; m < 12; ++m) { buf[m] = gather2<USE_D>(base, offs, u, diff); u += d; }
    }

    for (int outer = 0; outer < 5; ++outer) {
        if (q0 + outer * 12 >= Q) break;
        const int tb = t0 + outer * 12 * d;
#pragma unroll
        for (int ii = 0; ii < 12; ++ii) {
            const int t = tb + ii * d;           // position x: t, position y: t+1
            F2 g9[9];
#pragma unroll
            for (int j = 0; j < 9; ++j) g9[j] = buf[(ii + j) % 12];  // reg renaming only
            F2 Z[8];
            conv9(Z, g9, wq);
            if (t < T)     epi8<0>(Z, accM, cnt);
            if (t + 1 < T) epi8<1>(Z, accM, cnt);
            buf[ii] = gather2<USE_D>(base, offs, t + 8 * d, diff);
        }
    }

    float accC[8];
#pragma unroll
    for (int k = 0; k < 8; ++k) accC[k] = (float)((unsigned)(cnt >> (k * 8)) & 255u);

    // per-wave butterfly (combo wave-uniform; block may straddle combos)
#pragma unroll
    for (int k = 0; k < 8; ++k) {
#pragma unroll
        for (int sh = 1; sh < 64; sh <<= 1) {
            accM[k] += __shfl_xor(accM[k], sh, 64);
            accC[k] += __shfl_xor(accC[k], sh, 64);
        }
    }
    if ((tid & 63) == 0) {
        size_t bb = (size_t)b * 14336;
        int o = ga * 2;
#pragma unroll
        for (int k = 0; k < 8; ++k) {
            atomicAdd(&out[bb + (o * NH + h) * NK + k],       accM[k]);
            atomicAdd(&out[bb + ((o + 1) * NH + h) * NK + k], accC[k]);
        }
    }
}

__global__ void zeroK(float* __restrict__ out, int n) {
    int i = blockIdx.x * 256 + threadIdx.x;
    if (i < n) out[i] = 0.f;
}

extern "C" void kernel_launch(void* const* d_in, const int* in_sizes, int n_in,
                              void* d_out, int out_size, void* d_ws, size_t ws_size,
                              hipStream_t stream) {
    const float* X  = (const float*)d_in[0];
    const float* Wt = (const float*)d_in[1];
    const int*  idx = (const int*)d_in[2];
    float* out = (float*)d_out;
    float* Dws = (float*)d_ws;

    const size_t D_BYTES = (size_t)NB * NC * T0 * sizeof(float);   // 20.4 MB
    const bool useD = ws_size >= D_BYTES;

    zeroK<<<(out_size + 255) / 256, 256, 0, stream>>>(out, out_size);
    if (useD) {
        dim3 dg((T0 + 255) / 256, NB * NC);
        diffK<<<dg, 256, 0, stream>>>(X, Dws);
        kernA<true><<<A_TOTAL_BLOCKS, 256, 0, stream>>>(X, Dws, Wt, idx, out);
        kernB2<true><<<B2_BLOCKS, 256, 0, stream>>>(X, Dws, Wt, idx, out);
    } else {
        kernA<false><<<A_TOTAL_BLOCKS, 256, 0, stream>>>(X, Dws, Wt, idx, out);
        kernB2<false><<<B2_BLOCKS, 256, 0, stream>>>(X, Dws, Wt, idx, out);
    }
}